// Round 2
// baseline (253.662 us; speedup 1.0000x reference)
//
#include <hip/hip_runtime.h>
#include <hip/hip_bf16.h>

// Problem constants (fixed by reference)
#define BATCH 2
#define NPTS  8192
#define BN    (BATCH * NPTS)   // 16384
#define KNN   16
#define HEADS 4
#define DHEAD 32
#define HD    128              // HEADS*DHEAD
#define CIN   64
#define COUT  128
#define WCOLS 384              // [WqA1 | WkA1 | Wv]

// ---------------------------------------------------------------------------
// Kernel P: fold weights.
//   Wcat[64][384]: cols 0..127  = Wq@A1, 128..255 = Wk@A1, 256..383 = Wv
//   P2A1[3][128]  = P2@A1
//   cvec[128]     = b1 + bp2@A1     (constant part of pre-ReLU z)
// ---------------------------------------------------------------------------
__global__ void prep_kernel(const float* __restrict__ Wk,
                            const float* __restrict__ Wv,
                            const float* __restrict__ Wq,
                            const float* __restrict__ A1,
                            const float* __restrict__ b1,
                            const float* __restrict__ P2,
                            const float* __restrict__ bp2,
                            float* __restrict__ Wcat,
                            float* __restrict__ P2A1,
                            float* __restrict__ cvec) {
    int t = blockIdx.x * blockDim.x + threadIdx.x;
    if (t < CIN * WCOLS) {
        int i = t / WCOLS, j = t % WCOLS;
        float acc = 0.f;
        if (j < HD) {
            for (int m = 0; m < HD; ++m) acc += Wq[i*HD + m] * A1[m*HD + j];
        } else if (j < 2*HD) {
            int jj = j - HD;
            for (int m = 0; m < HD; ++m) acc += Wk[i*HD + m] * A1[m*HD + jj];
        } else {
            acc = Wv[i*HD + (j - 2*HD)];
        }
        Wcat[t] = acc;
    } else if (t < CIN*WCOLS + 3*HD) {
        int u = t - CIN*WCOLS;
        int r = u / HD, j = u % HD;
        float acc = 0.f;
        for (int m = 0; m < HD; ++m) acc += P2[r*HD + m] * A1[m*HD + j];
        P2A1[u] = acc;
    } else if (t < CIN*WCOLS + 3*HD + HD) {
        int j = t - (CIN*WCOLS + 3*HD);
        float acc = b1[j];
        for (int m = 0; m < HD; ++m) acc += bp2[m] * A1[m*HD + j];
        cvec[j] = acc;
    }
}

// ---------------------------------------------------------------------------
// Kernel A: QKV[p][0:128]   = F[p] @ (Wq@A1) + cvec   (pre-ReLU z, query part)
//           QKV[p][128:256] = F[p] @ (Wk@A1)
//           QKV[p][256:384] = F[p] @ Wv
// 32 points/block, 256 threads = (col 0..127, point-group 0..1), acc[16].
// ---------------------------------------------------------------------------
#define QPB 32
__global__ __launch_bounds__(256) void qkv_kernel(const float* __restrict__ F,
                                                  const float* __restrict__ Wcat,
                                                  const float* __restrict__ cvec,
                                                  float* __restrict__ QKV) {
    int p0 = blockIdx.x * QPB;
    int t = threadIdx.x;
    int col = t & 127, pg = t >> 7;
    __shared__ float fs[QPB][CIN];   // 8 KB
    for (int u = t; u < QPB * CIN; u += 256)
        fs[u >> 6][u & 63] = F[p0 * CIN + u];
    __syncthreads();

    #pragma unroll
    for (int r = 0; r < 3; ++r) {
        int j = r * HD + col;
        float base = (r == 0) ? cvec[col] : 0.f;
        float acc[16];
        #pragma unroll
        for (int i = 0; i < 16; ++i) acc[i] = base;
        #pragma unroll 4
        for (int i = 0; i < CIN; i += 4) {
            float w0 = Wcat[(i+0)*WCOLS + j];
            float w1 = Wcat[(i+1)*WCOLS + j];
            float w2 = Wcat[(i+2)*WCOLS + j];
            float w3 = Wcat[(i+3)*WCOLS + j];
            #pragma unroll
            for (int pt = 0; pt < 16; ++pt) {
                float4 f4 = *(const float4*)(&fs[pg*16 + pt][i]);
                acc[pt] += f4.x*w0 + f4.y*w1 + f4.z*w2 + f4.w*w3;
            }
        }
        #pragma unroll
        for (int pt = 0; pt < 16; ++pt)
            QKV[(p0 + pg*16 + pt) * WCOLS + j] = acc[pt];
    }
}

// ---------------------------------------------------------------------------
// Kernel B: per-point attention. 256 threads/block, one point per block.
// Thread layout: k = t>>4 (neighbor), g = t&15 (8-channel chunk, c0 = g*8).
// All 16 neighbor rows gather IN PARALLEL (no serial k loop).
// Logits via shfl_xor reduce over the 16-lane channel group; softmax by 4
// threads; weighted V reduce via shfl_xor(16/32) across k within each wave,
// then a tiny LDS combine across the 4 waves.
// fused[p] is written into QKV[p][0:128] (q-slot is dead after this block
// reads it; no other block touches row p's q columns).
// ---------------------------------------------------------------------------
__global__ __launch_bounds__(256) void attn_kernel(
        const float* __restrict__ xyzs, const int* __restrict__ kg,
        float* __restrict__ QKV,
        const float* __restrict__ P1, const float* __restrict__ bp1,
        const float* __restrict__ P2, const float* __restrict__ bp2,
        const float* __restrict__ P2A1,
        const float* __restrict__ A2, const float* __restrict__ b2) {
    int p = blockIdx.x;           // 0..BN-1
    int b = p >> 13;              // p / NPTS
    int t = threadIdx.x;
    int k = t >> 4;               // neighbor 0..15
    int g = t & 15;               // channel chunk 0..15
    int c0 = g * 8;
    int wave = t >> 6;
    int lane = t & 63;

    __shared__ float lg[KNN][HEADS];
    __shared__ float at_s[KNN][HEADS];
    __shared__ float part[4][HD];

    // ---- phase 1: parallel gather + z / vs in registers ----
    int idx = kg[p * KNN + k];
    int q = b * NPTS + idx;

    float r0 = xyzs[p*3+0] - xyzs[q*3+0];
    float r1 = xyzs[p*3+1] - xyzs[q*3+1];
    float r2 = xyzs[p*3+2] - xyzs[q*3+2];
    float h0 = fmaxf(r0*P1[0] + r1*P1[3] + r2*P1[6] + bp1[0], 0.f);
    float h1 = fmaxf(r0*P1[1] + r1*P1[4] + r2*P1[7] + bp1[1], 0.f);
    float h2 = fmaxf(r0*P1[2] + r1*P1[5] + r2*P1[8] + bp1[2], 0.f);

    float z[8], vsv[8];
    #pragma unroll
    for (int j = 0; j < 8; j += 4) {
        float4 qz = *(const float4*)(QKV + p*WCOLS + c0 + j);
        float4 kr = *(const float4*)(QKV + q*WCOLS + HD + c0 + j);
        float4 vr = *(const float4*)(QKV + q*WCOLS + 2*HD + c0 + j);
        float4 a0 = *(const float4*)(P2A1 + 0*HD + c0 + j);
        float4 a1 = *(const float4*)(P2A1 + 1*HD + c0 + j);
        float4 a2 = *(const float4*)(P2A1 + 2*HD + c0 + j);
        float4 q0 = *(const float4*)(P2   + 0*HD + c0 + j);
        float4 q1 = *(const float4*)(P2   + 1*HD + c0 + j);
        float4 q2 = *(const float4*)(P2   + 2*HD + c0 + j);
        float4 bp = *(const float4*)(bp2  + c0 + j);
        z[j+0] = fmaxf(qz.x - kr.x + h0*a0.x + h1*a1.x + h2*a2.x, 0.f);
        z[j+1] = fmaxf(qz.y - kr.y + h0*a0.y + h1*a1.y + h2*a2.y, 0.f);
        z[j+2] = fmaxf(qz.z - kr.z + h0*a0.z + h1*a1.z + h2*a2.z, 0.f);
        z[j+3] = fmaxf(qz.w - kr.w + h0*a0.w + h1*a1.w + h2*a2.w, 0.f);
        vsv[j+0] = vr.x + h0*q0.x + h1*q1.x + h2*q2.x + bp.x;
        vsv[j+1] = vr.y + h0*q0.y + h1*q1.y + h2*q2.y + bp.y;
        vsv[j+2] = vr.z + h0*q0.z + h1*q1.z + h2*q2.z + bp.z;
        vsv[j+3] = vr.w + h0*q0.w + h1*q1.w + h2*q2.w + bp.w;
    }

    // ---- phase 2: logits (partial dot + 16-lane butterfly reduce) ----
    float pl0 = 0.f, pl1 = 0.f, pl2 = 0.f, pl3 = 0.f;
    #pragma unroll
    for (int j = 0; j < 8; ++j) {
        float4 arow = *(const float4*)(A2 + (c0 + j) * HEADS);
        float zz = z[j];
        pl0 += zz * arow.x; pl1 += zz * arow.y;
        pl2 += zz * arow.z; pl3 += zz * arow.w;
    }
    #pragma unroll
    for (int off = 1; off < 16; off <<= 1) {
        pl0 += __shfl_xor(pl0, off, 64);
        pl1 += __shfl_xor(pl1, off, 64);
        pl2 += __shfl_xor(pl2, off, 64);
        pl3 += __shfl_xor(pl3, off, 64);
    }
    if (g == 0) {
        lg[k][0] = pl0 + b2[0];
        lg[k][1] = pl1 + b2[1];
        lg[k][2] = pl2 + b2[2];
        lg[k][3] = pl3 + b2[3];
    }
    __syncthreads();

    // ---- phase 3: softmax over K per head (4 threads) ----
    if (t < HEADS) {
        float m = -1e30f;
        #pragma unroll
        for (int kk = 0; kk < KNN; ++kk) m = fmaxf(m, lg[kk][t]);
        float e[KNN], s = 0.f;
        #pragma unroll
        for (int kk = 0; kk < KNN; ++kk) { e[kk] = __expf(lg[kk][t] - m); s += e[kk]; }
        float inv = 1.f / s;
        #pragma unroll
        for (int kk = 0; kk < KNN; ++kk) at_s[kk][t] = e[kk] * inv;
    }
    __syncthreads();

    // ---- phase 4: weighted reduce over neighbors ----
    float a = at_s[k][g >> 2];   // head = c0/32 = g/4
    float wv[8];
    #pragma unroll
    for (int j = 0; j < 8; ++j) wv[j] = a * vsv[j];
    #pragma unroll
    for (int j = 0; j < 8; ++j) {
        wv[j] += __shfl_xor(wv[j], 16, 64);
        wv[j] += __shfl_xor(wv[j], 32, 64);
    }
    if (lane < 16) {   // lane == g, k_local == 0: holds sum over this wave's 4 k
        *(float4*)(&part[wave][c0 + 0]) = make_float4(wv[0], wv[1], wv[2], wv[3]);
        *(float4*)(&part[wave][c0 + 4]) = make_float4(wv[4], wv[5], wv[6], wv[7]);
    }
    __syncthreads();

    if (t < HD) {
        float f = part[0][t] + part[1][t] + part[2][t] + part[3][t];
        QKV[p * WCOLS + t] = f;   // fused lives in the dead q-slot
    }
}

// ---------------------------------------------------------------------------
// Kernel C: out = fused @ Wout + bout.  fused[p] = QKV[p][0:128].
// 32 points/block, 256 threads = (col, point-group), fused tile in LDS.
// ---------------------------------------------------------------------------
#define OPB 32
__global__ __launch_bounds__(256) void out_kernel(const float* __restrict__ QKV,
                                                  const float* __restrict__ Wout,
                                                  const float* __restrict__ bout,
                                                  float* __restrict__ out) {
    int p0 = blockIdx.x * OPB;
    int t = threadIdx.x;
    int col = t & 127, pg = t >> 7;
    __shared__ float fl[OPB][HD];   // 16 KB
    for (int u = t; u < OPB * HD; u += 256)
        fl[u >> 7][u & 127] = QKV[(p0 + (u >> 7)) * WCOLS + (u & 127)];
    __syncthreads();

    float bb = bout[col];
    float acc[16];
    #pragma unroll
    for (int i = 0; i < 16; ++i) acc[i] = bb;
    #pragma unroll 4
    for (int j = 0; j < HD; j += 4) {
        float w0 = Wout[(j+0)*COUT + col];
        float w1 = Wout[(j+1)*COUT + col];
        float w2 = Wout[(j+2)*COUT + col];
        float w3 = Wout[(j+3)*COUT + col];
        #pragma unroll
        for (int i = 0; i < 16; ++i) {
            float4 f4 = *(const float4*)(&fl[pg*16 + i][j]);
            acc[i] += f4.x*w0 + f4.y*w1 + f4.z*w2 + f4.w*w3;
        }
    }
    #pragma unroll
    for (int i = 0; i < 16; ++i)
        out[(p0 + pg*16 + i) * COUT + col] = acc[i];
}

// ---------------------------------------------------------------------------
extern "C" void kernel_launch(void* const* d_in, const int* in_sizes, int n_in,
                              void* d_out, int out_size, void* d_ws, size_t ws_size,
                              hipStream_t stream) {
    const float* xyzs = (const float*)d_in[0];
    const float* feat = (const float*)d_in[1];
    const int*   kg   = (const int*)  d_in[2];
    const float* Wk   = (const float*)d_in[3];
    const float* Wv   = (const float*)d_in[4];
    const float* Wq   = (const float*)d_in[5];
    const float* A1   = (const float*)d_in[6];
    const float* b1   = (const float*)d_in[7];
    const float* A2   = (const float*)d_in[8];
    const float* b2   = (const float*)d_in[9];
    const float* P1   = (const float*)d_in[10];
    const float* bp1  = (const float*)d_in[11];
    const float* P2   = (const float*)d_in[12];
    const float* bp2  = (const float*)d_in[13];
    const float* Wout = (const float*)d_in[14];
    const float* bout = (const float*)d_in[15];
    float* out = (float*)d_out;

    float* ws   = (float*)d_ws;
    float* Wcat = ws;                      // 64*384      = 24576 floats
    float* P2A1 = ws + 24576;              // 3*128       = 384
    float* cvec = ws + 24960;              // 128
    float* QKV  = ws + 25088;              // 16384*384   = 6291456 floats (~24 MB)

    int prep_elems = CIN*WCOLS + 3*HD + HD;        // 25088
    prep_kernel<<<(prep_elems + 255) / 256, 256, 0, stream>>>(
        Wk, Wv, Wq, A1, b1, P2, bp2, Wcat, P2A1, cvec);

    qkv_kernel<<<BN / QPB, 256, 0, stream>>>(feat, Wcat, cvec, QKV);

    attn_kernel<<<BN, 256, 0, stream>>>(
        xyzs, kg, QKV, P1, bp1, P2, bp2, P2A1, A2, b2);

    out_kernel<<<BN / OPB, 256, 0, stream>>>(QKV, Wout, bout, out);
}

// Round 3
// 224.680 us; speedup vs baseline: 1.1290x; 1.1290x over previous
//
#include <hip/hip_runtime.h>
#include <hip/hip_bf16.h>

// Problem constants (fixed by reference)
#define BATCH 2
#define NPTS  8192
#define BN    (BATCH * NPTS)   // 16384
#define KNN   16
#define HEADS 4
#define HD    128              // HEADS*32
#define CIN   64
#define COUT  128
#define WCOLS 384              // [WqA1 | WkA1 | Wv]

static __device__ __forceinline__ unsigned short f2bf(float x) {
    unsigned u = __float_as_uint(x);
    u += 0x7fffu + ((u >> 16) & 1u);          // round-to-nearest-even
    return (unsigned short)(u >> 16);
}
static __device__ __forceinline__ float bf_lo(unsigned u) { return __uint_as_float(u << 16); }
static __device__ __forceinline__ float bf_hi(unsigned u) { return __uint_as_float(u & 0xffff0000u); }
static __device__ __forceinline__ unsigned pack2(float a, float b) {
    return (unsigned)f2bf(a) | ((unsigned)f2bf(b) << 16);
}

// ---------------------------------------------------------------------------
// Kernel P: fold weights.
//   Wcat[64][384]: cols 0..127 = Wq@A1, 128..255 = Wk@A1, 256..383 = Wv
//   P2A1[3][128]  = P2@A1
//   cvec[128]     = b1 + bp2@A1
// float4 on the row side + unroll so loads pipeline.
// ---------------------------------------------------------------------------
__global__ void prep_kernel(const float* __restrict__ Wk,
                            const float* __restrict__ Wv,
                            const float* __restrict__ Wq,
                            const float* __restrict__ A1,
                            const float* __restrict__ b1,
                            const float* __restrict__ P2,
                            const float* __restrict__ bp2,
                            float* __restrict__ Wcat,
                            float* __restrict__ P2A1,
                            float* __restrict__ cvec) {
    int t = blockIdx.x * blockDim.x + threadIdx.x;
    if (t < CIN * WCOLS) {
        int i = t / WCOLS, j = t % WCOLS;
        if (j < 2 * HD) {
            const float* w = (j < HD ? Wq : Wk) + i * HD;
            int jj = j & (HD - 1);
            float acc = 0.f;
            #pragma unroll 4
            for (int m = 0; m < HD; m += 4) {
                float4 wr = *(const float4*)(w + m);
                acc += wr.x * A1[(m+0)*HD + jj] + wr.y * A1[(m+1)*HD + jj]
                     + wr.z * A1[(m+2)*HD + jj] + wr.w * A1[(m+3)*HD + jj];
            }
            Wcat[t] = acc;
        } else {
            Wcat[t] = Wv[i * HD + (j - 2 * HD)];
        }
    } else if (t < CIN * WCOLS + 3 * HD) {
        int u = t - CIN * WCOLS;
        int r = u / HD, j = u % HD;
        const float* w = P2 + r * HD;
        float acc = 0.f;
        #pragma unroll 4
        for (int m = 0; m < HD; m += 4) {
            float4 wr = *(const float4*)(w + m);
            acc += wr.x * A1[(m+0)*HD + j] + wr.y * A1[(m+1)*HD + j]
                 + wr.z * A1[(m+2)*HD + j] + wr.w * A1[(m+3)*HD + j];
        }
        P2A1[u] = acc;
    } else if (t < CIN * WCOLS + 3 * HD + HD) {
        int j = t - (CIN * WCOLS + 3 * HD);
        float acc = b1[j];
        #pragma unroll 4
        for (int m = 0; m < HD; m += 4) {
            float4 wr = *(const float4*)(bp2 + m);
            acc += wr.x * A1[(m+0)*HD + j] + wr.y * A1[(m+1)*HD + j]
                 + wr.z * A1[(m+2)*HD + j] + wr.w * A1[(m+3)*HD + j];
        }
        cvec[j] = acc;
    }
}

// ---------------------------------------------------------------------------
// Kernel A: tiled GEMM  C[16384,384] = F[16384,64] @ Wcat[64,384].
// Grid (BN/64, 3): by=0 -> Q fp32 (+cvec), by=1 -> K bf16, by=2 -> V bf16.
// KV layout (bf16): KV[p][g*16 + 0..7] = K channels g*8..g*8+7,
//                   KV[p][g*16 + 8..15] = V channels g*8..g*8+7
// so the attn gather reads one contiguous 512B row per neighbor.
// Block 256 thr, thread tile 4 pts x 8 cols, A/B staged in LDS (~49KB).
// ---------------------------------------------------------------------------
#define TM 64
__global__ __launch_bounds__(256) void qkv_kernel(const float* __restrict__ F,
                                                  const float* __restrict__ Wcat,
                                                  const float* __restrict__ cvec,
                                                  float* __restrict__ Q,
                                                  unsigned short* __restrict__ KV) {
    int by = blockIdx.y;
    int p0 = blockIdx.x * TM;
    int t = threadIdx.x;
    __shared__ float As[TM][CIN + 1];   // [pt][ch], +1 pad
    __shared__ float Bs[CIN][HD];       // [k][col]

    #pragma unroll
    for (int r = 0; r < 4; ++r) {       // stage A: 64x64 fp32
        int v = t + r * 256;
        int pt = v >> 4, c4 = (v & 15) * 4;
        float4 fa = *(const float4*)(F + (p0 + pt) * CIN + c4);
        As[pt][c4+0] = fa.x; As[pt][c4+1] = fa.y;
        As[pt][c4+2] = fa.z; As[pt][c4+3] = fa.w;
    }
    #pragma unroll
    for (int r = 0; r < 8; ++r) {       // stage B: 64x128 slice
        int v = t + r * 256;
        int kk = v >> 5, j4 = (v & 31) * 4;
        *(float4*)(&Bs[kk][j4]) = *(const float4*)(Wcat + kk * WCOLS + by * HD + j4);
    }
    __syncthreads();

    int tx = t & 15, ty = t >> 4;
    int j0 = tx * 8, pm = ty * 4;
    float acc[4][8];
    #pragma unroll
    for (int i = 0; i < 4; ++i)
        #pragma unroll
        for (int j = 0; j < 8; ++j) acc[i][j] = 0.f;

    #pragma unroll 4
    for (int kk = 0; kk < CIN; ++kk) {
        float4 b0 = *(const float4*)(&Bs[kk][j0]);
        float4 b1 = *(const float4*)(&Bs[kk][j0 + 4]);
        float a0 = As[pm+0][kk], a1 = As[pm+1][kk];
        float a2 = As[pm+2][kk], a3 = As[pm+3][kk];
        acc[0][0] += a0*b0.x; acc[0][1] += a0*b0.y; acc[0][2] += a0*b0.z; acc[0][3] += a0*b0.w;
        acc[0][4] += a0*b1.x; acc[0][5] += a0*b1.y; acc[0][6] += a0*b1.z; acc[0][7] += a0*b1.w;
        acc[1][0] += a1*b0.x; acc[1][1] += a1*b0.y; acc[1][2] += a1*b0.z; acc[1][3] += a1*b0.w;
        acc[1][4] += a1*b1.x; acc[1][5] += a1*b1.y; acc[1][6] += a1*b1.z; acc[1][7] += a1*b1.w;
        acc[2][0] += a2*b0.x; acc[2][1] += a2*b0.y; acc[2][2] += a2*b0.z; acc[2][3] += a2*b0.w;
        acc[2][4] += a2*b1.x; acc[2][5] += a2*b1.y; acc[2][6] += a2*b1.z; acc[2][7] += a2*b1.w;
        acc[3][0] += a3*b0.x; acc[3][1] += a3*b0.y; acc[3][2] += a3*b0.z; acc[3][3] += a3*b0.w;
        acc[3][4] += a3*b1.x; acc[3][5] += a3*b1.y; acc[3][6] += a3*b1.z; acc[3][7] += a3*b1.w;
    }

    if (by == 0) {
        float4 c0v = *(const float4*)(cvec + j0);
        float4 c1v = *(const float4*)(cvec + j0 + 4);
        #pragma unroll
        for (int i = 0; i < 4; ++i) {
            int row = p0 + pm + i;
            float4 o0 = make_float4(acc[i][0]+c0v.x, acc[i][1]+c0v.y, acc[i][2]+c0v.z, acc[i][3]+c0v.w);
            float4 o1 = make_float4(acc[i][4]+c1v.x, acc[i][5]+c1v.y, acc[i][6]+c1v.z, acc[i][7]+c1v.w);
            *(float4*)(Q + row * HD + j0)     = o0;
            *(float4*)(Q + row * HD + j0 + 4) = o1;
        }
    } else {
        int off = (by == 1) ? 0 : 8;
        #pragma unroll
        for (int i = 0; i < 4; ++i) {
            int row = p0 + pm + i;
            uint4 u;
            u.x = pack2(acc[i][0], acc[i][1]);
            u.y = pack2(acc[i][2], acc[i][3]);
            u.z = pack2(acc[i][4], acc[i][5]);
            u.w = pack2(acc[i][6], acc[i][7]);
            *(uint4*)(KV + row * 256 + tx * 16 + off) = u;
        }
    }
}

// ---------------------------------------------------------------------------
// Kernel B: per-point attention. 256 threads/block: k = t>>4, g = t&15,
// channels c0 = g*8. bf16 KV gather: 2 adjacent 16B loads per lane from one
// contiguous 512B row per neighbor. Two barriers total: logits in LDS, then
// per-lane redundant softmax (no 4-thread phase), shuffle k-reduce, combine.
// ---------------------------------------------------------------------------
__global__ __launch_bounds__(256) void attn_kernel(
        const float* __restrict__ xyzs, const int* __restrict__ kg,
        const float* __restrict__ Q, const unsigned short* __restrict__ KV,
        const float* __restrict__ P1, const float* __restrict__ bp1,
        const float* __restrict__ P2, const float* __restrict__ bp2,
        const float* __restrict__ P2A1,
        const float* __restrict__ A2, const float* __restrict__ b2,
        float* __restrict__ FUSED) {
    int p = blockIdx.x;
    int b = p >> 13;              // p / NPTS
    int t = threadIdx.x;
    int k = t >> 4, g = t & 15, c0 = g * 8;
    int wave = t >> 6, lane = t & 63;

    __shared__ float lg[KNN][HEADS];
    __shared__ float part[4][HD];

    int idx = kg[p * KNN + k];
    int q = b * NPTS + idx;

    float r0 = xyzs[p*3+0] - xyzs[q*3+0];
    float r1 = xyzs[p*3+1] - xyzs[q*3+1];
    float r2 = xyzs[p*3+2] - xyzs[q*3+2];
    float h0 = fmaxf(r0*P1[0] + r1*P1[3] + r2*P1[6] + bp1[0], 0.f);
    float h1 = fmaxf(r0*P1[1] + r1*P1[4] + r2*P1[7] + bp1[1], 0.f);
    float h2 = fmaxf(r0*P1[2] + r1*P1[5] + r2*P1[8] + bp1[2], 0.f);

    const uint4* kvp = (const uint4*)(KV + q * 256 + g * 16);
    uint4 ku = kvp[0];
    uint4 vu = kvp[1];
    float kr[8] = { bf_lo(ku.x), bf_hi(ku.x), bf_lo(ku.y), bf_hi(ku.y),
                    bf_lo(ku.z), bf_hi(ku.z), bf_lo(ku.w), bf_hi(ku.w) };
    float vr[8] = { bf_lo(vu.x), bf_hi(vu.x), bf_lo(vu.y), bf_hi(vu.y),
                    bf_lo(vu.z), bf_hi(vu.z), bf_lo(vu.w), bf_hi(vu.w) };

    float z[8], vsv[8];
    #pragma unroll
    for (int j = 0; j < 8; j += 4) {
        float4 qz = *(const float4*)(Q + p*HD + c0 + j);
        float4 a0 = *(const float4*)(P2A1 + 0*HD + c0 + j);
        float4 a1 = *(const float4*)(P2A1 + 1*HD + c0 + j);
        float4 a2 = *(const float4*)(P2A1 + 2*HD + c0 + j);
        float4 q0 = *(const float4*)(P2   + 0*HD + c0 + j);
        float4 q1 = *(const float4*)(P2   + 1*HD + c0 + j);
        float4 q2 = *(const float4*)(P2   + 2*HD + c0 + j);
        float4 bp = *(const float4*)(bp2  + c0 + j);
        z[j+0] = fmaxf(qz.x - kr[j+0] + h0*a0.x + h1*a1.x + h2*a2.x, 0.f);
        z[j+1] = fmaxf(qz.y - kr[j+1] + h0*a0.y + h1*a1.y + h2*a2.y, 0.f);
        z[j+2] = fmaxf(qz.z - kr[j+2] + h0*a0.z + h1*a1.z + h2*a2.z, 0.f);
        z[j+3] = fmaxf(qz.w - kr[j+3] + h0*a0.w + h1*a1.w + h2*a2.w, 0.f);
        vsv[j+0] = vr[j+0] + h0*q0.x + h1*q1.x + h2*q2.x + bp.x;
        vsv[j+1] = vr[j+1] + h0*q0.y + h1*q1.y + h2*q2.y + bp.y;
        vsv[j+2] = vr[j+2] + h0*q0.z + h1*q1.z + h2*q2.z + bp.z;
        vsv[j+3] = vr[j+3] + h0*q0.w + h1*q1.w + h2*q2.w + bp.w;
    }

    // logits: partial dot + butterfly over the 16 g-lanes
    float pl0 = 0.f, pl1 = 0.f, pl2 = 0.f, pl3 = 0.f;
    #pragma unroll
    for (int j = 0; j < 8; ++j) {
        float4 arow = *(const float4*)(A2 + (c0 + j) * HEADS);
        float zz = z[j];
        pl0 += zz * arow.x; pl1 += zz * arow.y;
        pl2 += zz * arow.z; pl3 += zz * arow.w;
    }
    #pragma unroll
    for (int off = 1; off < 16; off <<= 1) {
        pl0 += __shfl_xor(pl0, off, 64);
        pl1 += __shfl_xor(pl1, off, 64);
        pl2 += __shfl_xor(pl2, off, 64);
        pl3 += __shfl_xor(pl3, off, 64);
    }
    if (g == 0) {
        lg[k][0] = pl0 + b2[0];
        lg[k][1] = pl1 + b2[1];
        lg[k][2] = pl2 + b2[2];
        lg[k][3] = pl3 + b2[3];
    }
    __syncthreads();

    // per-lane softmax over K for own head (redundant but barrier-free)
    int h = g >> 2;
    float m = -1e30f;
    #pragma unroll
    for (int kk = 0; kk < KNN; ++kk) m = fmaxf(m, lg[kk][h]);
    float s = 0.f;
    #pragma unroll
    for (int kk = 0; kk < KNN; ++kk) s += __expf(lg[kk][h] - m);
    float a = __expf(lg[k][h] - m) / s;

    // weighted reduce over neighbors: k-lanes within wave, then cross-wave
    float wv[8];
    #pragma unroll
    for (int j = 0; j < 8; ++j) wv[j] = a * vsv[j];
    #pragma unroll
    for (int j = 0; j < 8; ++j) {
        wv[j] += __shfl_xor(wv[j], 16, 64);
        wv[j] += __shfl_xor(wv[j], 32, 64);
    }
    if (lane < 16) {
        *(float4*)(&part[wave][c0 + 0]) = make_float4(wv[0], wv[1], wv[2], wv[3]);
        *(float4*)(&part[wave][c0 + 4]) = make_float4(wv[4], wv[5], wv[6], wv[7]);
    }
    __syncthreads();

    if (t < HD)
        FUSED[p * HD + t] = part[0][t] + part[1][t] + part[2][t] + part[3][t];
}

// ---------------------------------------------------------------------------
// Kernel C: out = FUSED @ Wout + bout.  Dense fp32 rows, coalesced staging.
// ---------------------------------------------------------------------------
#define OPB 32
__global__ __launch_bounds__(256) void out_kernel(const float* __restrict__ FUSED,
                                                  const float* __restrict__ Wout,
                                                  const float* __restrict__ bout,
                                                  float* __restrict__ out) {
    int p0 = blockIdx.x * OPB;
    int t = threadIdx.x;
    int col = t & 127, pg = t >> 7;
    __shared__ float fl[OPB][HD];   // 16 KB
    #pragma unroll
    for (int r = 0; r < 4; ++r) {
        int v = t + r * 256;        // float4 index over 32*128
        *(float4*)(&fl[v >> 5][(v & 31) * 4]) =
            *(const float4*)(FUSED + p0 * HD + v * 4);
    }
    __syncthreads();

    float bb = bout[col];
    float acc[16];
    #pragma unroll
    for (int i = 0; i < 16; ++i) acc[i] = bb;
    #pragma unroll 4
    for (int j = 0; j < HD; j += 4) {
        float w0 = Wout[(j+0)*COUT + col];
        float w1 = Wout[(j+1)*COUT + col];
        float w2 = Wout[(j+2)*COUT + col];
        float w3 = Wout[(j+3)*COUT + col];
        #pragma unroll
        for (int i = 0; i < 16; ++i) {
            float4 f4 = *(const float4*)(&fl[pg*16 + i][j]);
            acc[i] += f4.x*w0 + f4.y*w1 + f4.z*w2 + f4.w*w3;
        }
    }
    #pragma unroll
    for (int i = 0; i < 16; ++i)
        out[(p0 + pg*16 + i) * COUT + col] = acc[i];
}

// ---------------------------------------------------------------------------
extern "C" void kernel_launch(void* const* d_in, const int* in_sizes, int n_in,
                              void* d_out, int out_size, void* d_ws, size_t ws_size,
                              hipStream_t stream) {
    const float* xyzs = (const float*)d_in[0];
    const float* feat = (const float*)d_in[1];
    const int*   kg   = (const int*)  d_in[2];
    const float* Wk   = (const float*)d_in[3];
    const float* Wv   = (const float*)d_in[4];
    const float* Wq   = (const float*)d_in[5];
    const float* A1   = (const float*)d_in[6];
    const float* b1   = (const float*)d_in[7];
    const float* A2   = (const float*)d_in[8];
    const float* b2   = (const float*)d_in[9];
    const float* P1   = (const float*)d_in[10];
    const float* bp1  = (const float*)d_in[11];
    const float* P2   = (const float*)d_in[12];
    const float* bp2  = (const float*)d_in[13];
    const float* Wout = (const float*)d_in[14];
    const float* bout = (const float*)d_in[15];
    float* out = (float*)d_out;

    float* ws    = (float*)d_ws;
    float* Wcat  = ws;                       // 24576 floats
    float* P2A1  = ws + 24576;               // 384
    float* cvec  = ws + 24960;               // 128
    float* Q     = ws + 25088;               // BN*128 = 2097152 floats (8MB)
    float* FUSED = Q + (size_t)BN * HD;      // 8MB
    unsigned short* KV = (unsigned short*)(FUSED + (size_t)BN * HD);  // BN*256 bf16 (8MB)

    int prep_elems = CIN*WCOLS + 3*HD + HD;  // 25088
    prep_kernel<<<(prep_elems + 255) / 256, 256, 0, stream>>>(
        Wk, Wv, Wq, A1, b1, P2, bp2, Wcat, P2A1, cvec);

    qkv_kernel<<<dim3(BN / TM, 3), 256, 0, stream>>>(feat, Wcat, cvec, Q, KV);

    attn_kernel<<<BN, 256, 0, stream>>>(
        xyzs, kg, Q, KV, P1, bp1, P2, bp2, P2A1, A2, b2, FUSED);

    out_kernel<<<BN / OPB, 256, 0, stream>>>(FUSED, Wout, bout, out);
}

// Round 4
// 184.497 us; speedup vs baseline: 1.3749x; 1.2178x over previous
//
#include <hip/hip_runtime.h>
#include <hip/hip_bf16.h>

// Problem constants (fixed by reference)
#define BATCH 2
#define NPTS  8192
#define BN    (BATCH * NPTS)   // 16384
#define KNN   16
#define HEADS 4
#define HD    128              // HEADS*32
#define CIN   64
#define COUT  128
#define WCOLS 384              // [WqA1 | WkA1 | Wv]

static __device__ __forceinline__ unsigned short f2bf(float x) {
    unsigned u = __float_as_uint(x);
    u += 0x7fffu + ((u >> 16) & 1u);          // round-to-nearest-even
    return (unsigned short)(u >> 16);
}
static __device__ __forceinline__ float bf_lo(unsigned u) { return __uint_as_float(u << 16); }
static __device__ __forceinline__ float bf_hi(unsigned u) { return __uint_as_float(u & 0xffff0000u); }
static __device__ __forceinline__ unsigned pack2(float a, float b) {
    return (unsigned)f2bf(a) | ((unsigned)f2bf(b) << 16);
}

// DPP row ops (row = 16 lanes). row_ror:n ctrl = 0x120+n. Rotates never leave
// the row, so old/bound_ctrl don't matter.
template <int CTRL>
static __device__ __forceinline__ float dpp_mov(float x) {
    return __int_as_float(
        __builtin_amdgcn_update_dpp(0, __float_as_int(x), CTRL, 0xf, 0xf, false));
}
// After 4 ror steps every lane of the 16-lane row holds the row-wide result.
static __device__ __forceinline__ float ror_sum16(float x) {
    x += dpp_mov<0x128>(x);   // ror 8
    x += dpp_mov<0x124>(x);   // ror 4
    x += dpp_mov<0x122>(x);   // ror 2
    x += dpp_mov<0x121>(x);   // ror 1
    return x;
}
static __device__ __forceinline__ float ror_max16(float x) {
    x = fmaxf(x, dpp_mov<0x128>(x));
    x = fmaxf(x, dpp_mov<0x124>(x));
    x = fmaxf(x, dpp_mov<0x122>(x));
    x = fmaxf(x, dpp_mov<0x121>(x));
    return x;
}

// ---------------------------------------------------------------------------
// Kernel P: fold weights.
//   Wcat[64][384]: cols 0..127 = Wq@A1, 128..255 = Wk@A1, 256..383 = Wv
//   P2A1[3][128]  = P2@A1
//   cvec[128]     = b1 + bp2@A1
// ---------------------------------------------------------------------------
__global__ void prep_kernel(const float* __restrict__ Wk,
                            const float* __restrict__ Wv,
                            const float* __restrict__ Wq,
                            const float* __restrict__ A1,
                            const float* __restrict__ b1,
                            const float* __restrict__ P2,
                            const float* __restrict__ bp2,
                            float* __restrict__ Wcat,
                            float* __restrict__ P2A1,
                            float* __restrict__ cvec) {
    int t = blockIdx.x * blockDim.x + threadIdx.x;
    if (t < CIN * WCOLS) {
        int i = t / WCOLS, j = t % WCOLS;
        if (j < 2 * HD) {
            const float* w = (j < HD ? Wq : Wk) + i * HD;
            int jj = j & (HD - 1);
            float acc = 0.f;
            #pragma unroll 4
            for (int m = 0; m < HD; m += 4) {
                float4 wr = *(const float4*)(w + m);
                acc += wr.x * A1[(m+0)*HD + jj] + wr.y * A1[(m+1)*HD + jj]
                     + wr.z * A1[(m+2)*HD + jj] + wr.w * A1[(m+3)*HD + jj];
            }
            Wcat[t] = acc;
        } else {
            Wcat[t] = Wv[i * HD + (j - 2 * HD)];
        }
    } else if (t < CIN * WCOLS + 3 * HD) {
        int u = t - CIN * WCOLS;
        int r = u / HD, j = u % HD;
        const float* w = P2 + r * HD;
        float acc = 0.f;
        #pragma unroll 4
        for (int m = 0; m < HD; m += 4) {
            float4 wr = *(const float4*)(w + m);
            acc += wr.x * A1[(m+0)*HD + j] + wr.y * A1[(m+1)*HD + j]
                 + wr.z * A1[(m+2)*HD + j] + wr.w * A1[(m+3)*HD + j];
        }
        P2A1[u] = acc;
    } else if (t < CIN * WCOLS + 3 * HD + HD) {
        int j = t - (CIN * WCOLS + 3 * HD);
        float acc = b1[j];
        #pragma unroll 4
        for (int m = 0; m < HD; m += 4) {
            float4 wr = *(const float4*)(bp2 + m);
            acc += wr.x * A1[(m+0)*HD + j] + wr.y * A1[(m+1)*HD + j]
                 + wr.z * A1[(m+2)*HD + j] + wr.w * A1[(m+3)*HD + j];
        }
        cvec[j] = acc;
    }
}

// ---------------------------------------------------------------------------
// Kernel A: tiled GEMM  C[16384,384] = F[16384,64] @ Wcat[64,384].
// Grid (BN/64, 3): by=0 -> Q fp32 (+cvec), by=1 -> K bf16, by=2 -> V bf16.
// KV layout (bf16): KV[p][g*16 + 0..7] = K ch g*8.., [g*16+8..15] = V ch g*8..
// ---------------------------------------------------------------------------
#define TM 64
__global__ __launch_bounds__(256) void qkv_kernel(const float* __restrict__ F,
                                                  const float* __restrict__ Wcat,
                                                  const float* __restrict__ cvec,
                                                  float* __restrict__ Q,
                                                  unsigned short* __restrict__ KV) {
    int by = blockIdx.y;
    int p0 = blockIdx.x * TM;
    int t = threadIdx.x;
    __shared__ float As[TM][CIN + 1];
    __shared__ float Bs[CIN][HD];

    #pragma unroll
    for (int r = 0; r < 4; ++r) {
        int v = t + r * 256;
        int pt = v >> 4, c4 = (v & 15) * 4;
        float4 fa = *(const float4*)(F + (p0 + pt) * CIN + c4);
        As[pt][c4+0] = fa.x; As[pt][c4+1] = fa.y;
        As[pt][c4+2] = fa.z; As[pt][c4+3] = fa.w;
    }
    #pragma unroll
    for (int r = 0; r < 8; ++r) {
        int v = t + r * 256;
        int kk = v >> 5, j4 = (v & 31) * 4;
        *(float4*)(&Bs[kk][j4]) = *(const float4*)(Wcat + kk * WCOLS + by * HD + j4);
    }
    __syncthreads();

    int tx = t & 15, ty = t >> 4;
    int j0 = tx * 8, pm = ty * 4;
    float acc[4][8];
    #pragma unroll
    for (int i = 0; i < 4; ++i)
        #pragma unroll
        for (int j = 0; j < 8; ++j) acc[i][j] = 0.f;

    #pragma unroll 4
    for (int kk = 0; kk < CIN; ++kk) {
        float4 b0 = *(const float4*)(&Bs[kk][j0]);
        float4 b1 = *(const float4*)(&Bs[kk][j0 + 4]);
        float a0 = As[pm+0][kk], a1 = As[pm+1][kk];
        float a2 = As[pm+2][kk], a3 = As[pm+3][kk];
        acc[0][0] += a0*b0.x; acc[0][1] += a0*b0.y; acc[0][2] += a0*b0.z; acc[0][3] += a0*b0.w;
        acc[0][4] += a0*b1.x; acc[0][5] += a0*b1.y; acc[0][6] += a0*b1.z; acc[0][7] += a0*b1.w;
        acc[1][0] += a1*b0.x; acc[1][1] += a1*b0.y; acc[1][2] += a1*b0.z; acc[1][3] += a1*b0.w;
        acc[1][4] += a1*b1.x; acc[1][5] += a1*b1.y; acc[1][6] += a1*b1.z; acc[1][7] += a1*b1.w;
        acc[2][0] += a2*b0.x; acc[2][1] += a2*b0.y; acc[2][2] += a2*b0.z; acc[2][3] += a2*b0.w;
        acc[2][4] += a2*b1.x; acc[2][5] += a2*b1.y; acc[2][6] += a2*b1.z; acc[2][7] += a2*b1.w;
        acc[3][0] += a3*b0.x; acc[3][1] += a3*b0.y; acc[3][2] += a3*b0.z; acc[3][3] += a3*b0.w;
        acc[3][4] += a3*b1.x; acc[3][5] += a3*b1.y; acc[3][6] += a3*b1.z; acc[3][7] += a3*b1.w;
    }

    if (by == 0) {
        float4 c0v = *(const float4*)(cvec + j0);
        float4 c1v = *(const float4*)(cvec + j0 + 4);
        #pragma unroll
        for (int i = 0; i < 4; ++i) {
            int row = p0 + pm + i;
            float4 o0 = make_float4(acc[i][0]+c0v.x, acc[i][1]+c0v.y, acc[i][2]+c0v.z, acc[i][3]+c0v.w);
            float4 o1 = make_float4(acc[i][4]+c1v.x, acc[i][5]+c1v.y, acc[i][6]+c1v.z, acc[i][7]+c1v.w);
            *(float4*)(Q + row * HD + j0)     = o0;
            *(float4*)(Q + row * HD + j0 + 4) = o1;
        }
    } else {
        int off = (by == 1) ? 0 : 8;
        #pragma unroll
        for (int i = 0; i < 4; ++i) {
            int row = p0 + pm + i;
            uint4 u;
            u.x = pack2(acc[i][0], acc[i][1]);
            u.y = pack2(acc[i][2], acc[i][3]);
            u.z = pack2(acc[i][4], acc[i][5]);
            u.w = pack2(acc[i][6], acc[i][7]);
            *(uint4*)(KV + row * 256 + tx * 16 + off) = u;
        }
    }
}

// ---------------------------------------------------------------------------
// Kernel B: per-point attention, DPP edition. 256 thr/block, one point.
// Thread layout: g = t>>4 (8-channel chunk), k = t&15 (neighbor) -> the 16
// neighbors are one DPP row; head h = g>>2 = wave index w.
//   phase A: gather K/V bf16, z = relu(q - k + h.P2A1); logit partials over
//            own 8 ch; xor16/32 swizzle sums the wave's 4 g-rows; row 0
//            writes per-wave float4 partial to LDS.
//   phase B: wave 0 (lane = h*16+k) sums 4 wave partials, DPP-row softmax
//            over k (1 exp/thread), also DPP-reduces hbar[h] = sum_k a_k h_k.
//   phase C: wv[j] = ror_sum16(a * v); fused = wv + hbar.P2 + bp2 (uses
//            sum_k a_k = 1 to fold pe); lane k==0 stores 8 floats.
// ---------------------------------------------------------------------------
__global__ __launch_bounds__(256) void attn_kernel(
        const float* __restrict__ xyzs, const int* __restrict__ kg,
        const float* __restrict__ Q, const unsigned short* __restrict__ KV,
        const float* __restrict__ P1, const float* __restrict__ bp1,
        const float* __restrict__ P2, const float* __restrict__ bp2,
        const float* __restrict__ P2A1,
        const float* __restrict__ A2, const float* __restrict__ b2,
        float* __restrict__ FUSED) {
    int p = blockIdx.x;
    int b = p >> 13;              // p / NPTS
    int t = threadIdx.x;
    int g = t >> 4, k = t & 15, c0 = g * 8;
    int w = t >> 6;               // wave = head of this thread's channels
    int lane = t & 63;

    __shared__ float4 A2s[HD];        // A2 rows (4 floats each)
    __shared__ float4 lgp[4][16];     // [wave][k] logit partials (4 heads)
    __shared__ float4 hs16[16];       // per-neighbor h vector
    __shared__ float  ats[64];        // [h][k] attention weights
    __shared__ float4 hbf[4];         // [h] hbar

    // stage A2 (one float4 per row)
    if (t < HD) A2s[t] = *(const float4*)(A2 + t * 4);

    // ---- phase A: gather + z + logit partials ----
    int idx = kg[p * KNN + k];
    int q = b * NPTS + idx;

    float r0 = xyzs[p*3+0] - xyzs[q*3+0];
    float r1 = xyzs[p*3+1] - xyzs[q*3+1];
    float r2 = xyzs[p*3+2] - xyzs[q*3+2];
    float h0 = fmaxf(r0*P1[0] + r1*P1[3] + r2*P1[6] + bp1[0], 0.f);
    float h1 = fmaxf(r0*P1[1] + r1*P1[4] + r2*P1[7] + bp1[1], 0.f);
    float h2 = fmaxf(r0*P1[2] + r1*P1[5] + r2*P1[8] + bp1[2], 0.f);
    if (g == 0) hs16[k] = make_float4(h0, h1, h2, 0.f);

    const uint4* kvp = (const uint4*)(KV + q * 256 + g * 16);
    uint4 ku = kvp[0];
    uint4 vu = kvp[1];   // stays packed until phase C

    float qz[8], wa0[8], wa1[8], wa2[8];
    *(float4*)(qz)     = *(const float4*)(Q + p*HD + c0);
    *(float4*)(qz + 4) = *(const float4*)(Q + p*HD + c0 + 4);
    *(float4*)(wa0)     = *(const float4*)(P2A1 + 0*HD + c0);
    *(float4*)(wa0 + 4) = *(const float4*)(P2A1 + 0*HD + c0 + 4);
    *(float4*)(wa1)     = *(const float4*)(P2A1 + 1*HD + c0);
    *(float4*)(wa1 + 4) = *(const float4*)(P2A1 + 1*HD + c0 + 4);
    *(float4*)(wa2)     = *(const float4*)(P2A1 + 2*HD + c0);
    *(float4*)(wa2 + 4) = *(const float4*)(P2A1 + 2*HD + c0 + 4);

    float kr[8] = { bf_lo(ku.x), bf_hi(ku.x), bf_lo(ku.y), bf_hi(ku.y),
                    bf_lo(ku.z), bf_hi(ku.z), bf_lo(ku.w), bf_hi(ku.w) };

    __syncthreads();   // A2s / hs16 visible

    float pl0 = 0.f, pl1 = 0.f, pl2 = 0.f, pl3 = 0.f;
    #pragma unroll
    for (int j = 0; j < 8; ++j) {
        float z = fmaxf(qz[j] - kr[j] + h0*wa0[j] + h1*wa1[j] + h2*wa2[j], 0.f);
        float4 ar = A2s[c0 + j];
        pl0 += z * ar.x; pl1 += z * ar.y; pl2 += z * ar.z; pl3 += z * ar.w;
    }
    // sum the wave's 4 g-rows (cross-row -> ds_swizzle; 8 DS total)
    pl0 += __shfl_xor(pl0, 16, 64); pl0 += __shfl_xor(pl0, 32, 64);
    pl1 += __shfl_xor(pl1, 16, 64); pl1 += __shfl_xor(pl1, 32, 64);
    pl2 += __shfl_xor(pl2, 16, 64); pl2 += __shfl_xor(pl2, 32, 64);
    pl3 += __shfl_xor(pl3, 16, 64); pl3 += __shfl_xor(pl3, 32, 64);
    if (lane < 16) lgp[w][lane] = make_float4(pl0, pl1, pl2, pl3);
    __syncthreads();

    // ---- phase B: softmax (wave 0 only; k row-local => DPP) ----
    if (t < 64) {
        int hh = t >> 4, kk = t & 15;
        const float* lp = (const float*)lgp;
        float lgt = b2[hh] + lp[0*64 + kk*4 + hh] + lp[1*64 + kk*4 + hh]
                           + lp[2*64 + kk*4 + hh] + lp[3*64 + kk*4 + hh];
        float m = ror_max16(lgt);
        float e = __expf(lgt - m);
        float s = ror_sum16(e);
        float a = e / s;
        ats[t] = a;                      // ats[hh*16 + kk]
        float4 hv = hs16[kk];
        float hb0 = ror_sum16(a * hv.x);
        float hb1 = ror_sum16(a * hv.y);
        float hb2 = ror_sum16(a * hv.z);
        if (kk == 0) hbf[hh] = make_float4(hb0, hb1, hb2, 0.f);
    }
    __syncthreads();

    // ---- phase C: weighted V reduce over the k-row (pure DPP) ----
    float a = ats[w * 16 + k];           // head == wave
    float vr[8] = { bf_lo(vu.x), bf_hi(vu.x), bf_lo(vu.y), bf_hi(vu.y),
                    bf_lo(vu.z), bf_hi(vu.z), bf_lo(vu.w), bf_hi(vu.w) };
    float wv[8];
    #pragma unroll
    for (int j = 0; j < 8; ++j) wv[j] = ror_sum16(a * vr[j]);

    if (k == 0) {
        float4 hb = hbf[w];
        float q0[8], q1[8], q2[8], bpv[8];
        *(float4*)(q0)     = *(const float4*)(P2 + 0*HD + c0);
        *(float4*)(q0 + 4) = *(const float4*)(P2 + 0*HD + c0 + 4);
        *(float4*)(q1)     = *(const float4*)(P2 + 1*HD + c0);
        *(float4*)(q1 + 4) = *(const float4*)(P2 + 1*HD + c0 + 4);
        *(float4*)(q2)     = *(const float4*)(P2 + 2*HD + c0);
        *(float4*)(q2 + 4) = *(const float4*)(P2 + 2*HD + c0 + 4);
        *(float4*)(bpv)     = *(const float4*)(bp2 + c0);
        *(float4*)(bpv + 4) = *(const float4*)(bp2 + c0 + 4);
        float f[8];
        #pragma unroll
        for (int j = 0; j < 8; ++j)
            f[j] = wv[j] + hb.x*q0[j] + hb.y*q1[j] + hb.z*q2[j] + bpv[j];
        *(float4*)(FUSED + p*HD + c0)     = *(float4*)(f);
        *(float4*)(FUSED + p*HD + c0 + 4) = *(float4*)(f + 4);
    }
}

// ---------------------------------------------------------------------------
// Kernel C: out = FUSED @ Wout + bout.
// ---------------------------------------------------------------------------
#define OPB 32
__global__ __launch_bounds__(256) void out_kernel(const float* __restrict__ FUSED,
                                                  const float* __restrict__ Wout,
                                                  const float* __restrict__ bout,
                                                  float* __restrict__ out) {
    int p0 = blockIdx.x * OPB;
    int t = threadIdx.x;
    int col = t & 127, pg = t >> 7;
    __shared__ float fl[OPB][HD];
    #pragma unroll
    for (int r = 0; r < 4; ++r) {
        int v = t + r * 256;
        *(float4*)(&fl[v >> 5][(v & 31) * 4]) =
            *(const float4*)(FUSED + p0 * HD + v * 4);
    }
    __syncthreads();

    float bb = bout[col];
    float acc[16];
    #pragma unroll
    for (int i = 0; i < 16; ++i) acc[i] = bb;
    #pragma unroll 4
    for (int j = 0; j < HD; j += 4) {
        float w0 = Wout[(j+0)*COUT + col];
        float w1 = Wout[(j+1)*COUT + col];
        float w2 = Wout[(j+2)*COUT + col];
        float w3 = Wout[(j+3)*COUT + col];
        #pragma unroll
        for (int i = 0; i < 16; ++i) {
            float4 f4 = *(const float4*)(&fl[pg*16 + i][j]);
            acc[i] += f4.x*w0 + f4.y*w1 + f4.z*w2 + f4.w*w3;
        }
    }
    #pragma unroll
    for (int i = 0; i < 16; ++i)
        out[(p0 + pg*16 + i) * COUT + col] = acc[i];
}

// ---------------------------------------------------------------------------
extern "C" void kernel_launch(void* const* d_in, const int* in_sizes, int n_in,
                              void* d_out, int out_size, void* d_ws, size_t ws_size,
                              hipStream_t stream) {
    const float* xyzs = (const float*)d_in[0];
    const float* feat = (const float*)d_in[1];
    const int*   kg   = (const int*)  d_in[2];
    const float* Wk   = (const float*)d_in[3];
    const float* Wv   = (const float*)d_in[4];
    const float* Wq   = (const float*)d_in[5];
    const float* A1   = (const float*)d_in[6];
    const float* b1   = (const float*)d_in[7];
    const float* A2   = (const float*)d_in[8];
    const float* b2   = (const float*)d_in[9];
    const float* P1   = (const float*)d_in[10];
    const float* bp1  = (const float*)d_in[11];
    const float* P2   = (const float*)d_in[12];
    const float* bp2  = (const float*)d_in[13];
    const float* Wout = (const float*)d_in[14];
    const float* bout = (const float*)d_in[15];
    float* out = (float*)d_out;

    float* ws    = (float*)d_ws;
    float* Wcat  = ws;                       // 24576 floats
    float* P2A1  = ws + 24576;               // 384
    float* cvec  = ws + 24960;               // 128
    float* Q     = ws + 25088;               // BN*128 fp32 (8MB)
    float* FUSED = Q + (size_t)BN * HD;      // BN*128 fp32 (8MB)
    unsigned short* KV = (unsigned short*)(FUSED + (size_t)BN * HD);  // BN*256 bf16 (8MB)

    int prep_elems = CIN*WCOLS + 3*HD + HD;  // 25088
    prep_kernel<<<(prep_elems + 255) / 256, 256, 0, stream>>>(
        Wk, Wv, Wq, A1, b1, P2, bp2, Wcat, P2A1, cvec);

    qkv_kernel<<<dim3(BN / TM, 3), 256, 0, stream>>>(feat, Wcat, cvec, Q, KV);

    attn_kernel<<<BN, 256, 0, stream>>>(
        xyzs, kg, Q, KV, P1, bp1, P2, bp2, P2A1, A2, b2, FUSED);

    out_kernel<<<BN / OPB, 256, 0, stream>>>(FUSED, Wout, bout, out);
}

// Round 5
// 158.377 us; speedup vs baseline: 1.6016x; 1.1649x over previous
//
#include <hip/hip_runtime.h>
#include <hip/hip_bf16.h>

// Problem constants (fixed by reference)
#define BATCH 2
#define NPTS  8192
#define BN    (BATCH * NPTS)   // 16384
#define KNN   16
#define HEADS 4
#define HD    128              // HEADS*32
#define CIN   64
#define COUT  128
#define WCOLS 384              // [WqA1 | WkA1 | Wv] columns

using short8  = __attribute__((ext_vector_type(8))) short;
using float4v = __attribute__((ext_vector_type(4))) float;

static __device__ __forceinline__ unsigned short f2bf(float x) {
    unsigned u = __float_as_uint(x);
    u += 0x7fffu + ((u >> 16) & 1u);          // round-to-nearest-even
    return (unsigned short)(u >> 16);
}
static __device__ __forceinline__ float bf_lo(unsigned u) { return __uint_as_float(u << 16); }
static __device__ __forceinline__ float bf_hi(unsigned u) { return __uint_as_float(u & 0xffff0000u); }
static __device__ __forceinline__ unsigned pack2(float a, float b) {
    return (unsigned)f2bf(a) | ((unsigned)f2bf(b) << 16);
}

// DPP row ops (row = 16 lanes). row_ror:n ctrl = 0x120+n.
template <int CTRL>
static __device__ __forceinline__ float dpp_mov(float x) {
    return __int_as_float(
        __builtin_amdgcn_update_dpp(0, __float_as_int(x), CTRL, 0xf, 0xf, false));
}
static __device__ __forceinline__ float ror_sum16(float x) {
    x += dpp_mov<0x128>(x);
    x += dpp_mov<0x124>(x);
    x += dpp_mov<0x122>(x);
    x += dpp_mov<0x121>(x);
    return x;
}
static __device__ __forceinline__ float ror_max16(float x) {
    x = fmaxf(x, dpp_mov<0x128>(x));
    x = fmaxf(x, dpp_mov<0x124>(x));
    x = fmaxf(x, dpp_mov<0x122>(x));
    x = fmaxf(x, dpp_mov<0x121>(x));
    return x;
}

// ---------------------------------------------------------------------------
// Kernel P: fold weights into MFMA-ready transposed bf16 operands.
//   WcatT[n][k] bf16, n in [0,384), k in [0,64):
//        n<128: (Wq@A1)[k][n] ; n<256: (Wk@A1)[k][n-128] ; else Wv[k][n-256]
//   WoutT[n][k] bf16 = Wout[k][n]          (n,k in [0,128))
//   P2A1[3][128] fp32 = P2@A1
//   cvec[128] fp32 = b1 + bp2@A1
// ---------------------------------------------------------------------------
__global__ void prep_kernel(const float* __restrict__ Wk,
                            const float* __restrict__ Wv,
                            const float* __restrict__ Wq,
                            const float* __restrict__ A1,
                            const float* __restrict__ b1,
                            const float* __restrict__ P2,
                            const float* __restrict__ bp2,
                            const float* __restrict__ Wout,
                            unsigned short* __restrict__ WcatT,
                            unsigned short* __restrict__ WoutT,
                            float* __restrict__ P2A1,
                            float* __restrict__ cvec) {
    int t = blockIdx.x * blockDim.x + threadIdx.x;
    if (t < WCOLS * CIN) {                     // WcatT: u = n*64 + kk
        int n = t >> 6, kk = t & 63;
        float val;
        if (n < 2 * HD) {
            const float* w = (n < HD ? Wq : Wk) + kk * HD;
            int jj = n & (HD - 1);
            float acc = 0.f;
            #pragma unroll 4
            for (int m = 0; m < HD; m += 4) {
                float4 wr = *(const float4*)(w + m);
                acc += wr.x * A1[(m+0)*HD + jj] + wr.y * A1[(m+1)*HD + jj]
                     + wr.z * A1[(m+2)*HD + jj] + wr.w * A1[(m+3)*HD + jj];
            }
            val = acc;
        } else {
            val = Wv[kk * HD + (n - 2 * HD)];
        }
        WcatT[t] = f2bf(val);
    } else if (t < WCOLS * CIN + COUT * HD) {  // WoutT: u = n*128 + kk
        int u = t - WCOLS * CIN;
        int n = u >> 7, kk = u & 127;
        WoutT[u] = f2bf(Wout[kk * COUT + n]);
    } else if (t < WCOLS * CIN + COUT * HD + 3 * HD) {
        int u = t - (WCOLS * CIN + COUT * HD);
        int r = u / HD, j = u % HD;
        const float* w = P2 + r * HD;
        float acc = 0.f;
        #pragma unroll 4
        for (int m = 0; m < HD; m += 4) {
            float4 wr = *(const float4*)(w + m);
            acc += wr.x * A1[(m+0)*HD + j] + wr.y * A1[(m+1)*HD + j]
                 + wr.z * A1[(m+2)*HD + j] + wr.w * A1[(m+3)*HD + j];
        }
        P2A1[u] = acc;
    } else if (t < WCOLS * CIN + COUT * HD + 3 * HD + HD) {
        int j = t - (WCOLS * CIN + COUT * HD + 3 * HD);
        float acc = b1[j];
        #pragma unroll 4
        for (int m = 0; m < HD; m += 4) {
            float4 wr = *(const float4*)(bp2 + m);
            acc += wr.x * A1[(m+0)*HD + j] + wr.y * A1[(m+1)*HD + j]
                 + wr.z * A1[(m+2)*HD + j] + wr.w * A1[(m+3)*HD + j];
        }
        cvec[j] = acc;
    }
}

// ---------------------------------------------------------------------------
// Kernel A (MFMA): QKVb[16384][384] bf16 = bf16(F) @ Wcat (+cvec on n<128).
// n<128: pre-ReLU z query part; 128..255: K; 256..383: V.
// Block: 64 rows, 4 waves (wave = 16 rows), K=64 (2 mfma/nt), nt=24.
// A-frag: lane(m=l&15, k=quad*8..+7); B stored transposed [n][k] likewise.
// LDS stride 88 elems (176 B, 16B-multiple, 2-way bank alias on frag reads).
// ---------------------------------------------------------------------------
#define AK 88
__global__ __launch_bounds__(256) void qkv_kernel(const float* __restrict__ F,
                                                  const unsigned short* __restrict__ WcatT,
                                                  const float* __restrict__ cvec,
                                                  unsigned short* __restrict__ QKVb) {
    __shared__ unsigned short Af[64 * AK];     // 11.3 KB
    __shared__ unsigned short Bf[WCOLS * AK];  // 67.6 KB
    int p0 = blockIdx.x * 64;
    int t = threadIdx.x;

    // stage A: 64x64 fp32 -> bf16
    #pragma unroll
    for (int i = 0; i < 4; ++i) {
        int v = t + i * 256;
        int row = v >> 4, c4 = (v & 15) * 4;
        float4 fa = *(const float4*)(F + (p0 + row) * CIN + c4);
        uint2 u = make_uint2(pack2(fa.x, fa.y), pack2(fa.z, fa.w));
        *(uint2*)(&Af[row * AK + c4]) = u;
    }
    // stage B: 384x64 bf16
    #pragma unroll
    for (int i = 0; i < 12; ++i) {
        int v = t + i * 256;                   // uint4 index: n = v>>3, j16 = v&7
        int n = v >> 3, j16 = v & 7;
        *(uint4*)(&Bf[n * AK + j16 * 8]) = ((const uint4*)WcatT)[v];
    }
    __syncthreads();

    int w = t >> 6, l = t & 63;
    int ml = l & 15, quad = l >> 4;
    int m0 = w * 16;

    short8 a0 = *(const short8*)(&Af[(m0 + ml) * AK + quad * 8]);
    short8 a1 = *(const short8*)(&Af[(m0 + ml) * AK + 32 + quad * 8]);

    #pragma unroll
    for (int nt = 0; nt < 24; ++nt) {
        short8 b0 = *(const short8*)(&Bf[(nt * 16 + ml) * AK + quad * 8]);
        short8 b1 = *(const short8*)(&Bf[(nt * 16 + ml) * AK + 32 + quad * 8]);
        float4v acc = {0.f, 0.f, 0.f, 0.f};
        acc = __builtin_amdgcn_mfma_f32_16x16x32_bf16(a0, b0, acc, 0, 0, 0);
        acc = __builtin_amdgcn_mfma_f32_16x16x32_bf16(a1, b1, acc, 0, 0, 0);
        int n = nt * 16 + ml;
        float cadd = (n < HD) ? cvec[n] : 0.f;
        #pragma unroll
        for (int r = 0; r < 4; ++r) {
            int row = p0 + m0 + quad * 4 + r;
            QKVb[row * WCOLS + n] = f2bf(acc[r] + cadd);
        }
    }
}

// ---------------------------------------------------------------------------
// Kernel B: per-point attention (DPP, unchanged structure from R4).
// Reads bf16 QKVb: q at [p][c0], K at [q][128+c0], V at [q][256+c0].
// Writes FUSEDb bf16.
// ---------------------------------------------------------------------------
__global__ __launch_bounds__(256) void attn_kernel(
        const float* __restrict__ xyzs, const int* __restrict__ kg,
        const unsigned short* __restrict__ QKVb,
        const float* __restrict__ P1, const float* __restrict__ bp1,
        const float* __restrict__ P2, const float* __restrict__ bp2,
        const float* __restrict__ P2A1,
        const float* __restrict__ A2, const float* __restrict__ b2,
        unsigned short* __restrict__ FUSEDb) {
    int p = blockIdx.x;
    int b = p >> 13;              // p / NPTS
    int t = threadIdx.x;
    int g = t >> 4, k = t & 15, c0 = g * 8;
    int w = t >> 6;               // wave = head of this thread's channels
    int lane = t & 63;

    __shared__ float4 A2s[HD];
    __shared__ float4 lgp[4][16];
    __shared__ float4 hs16[16];
    __shared__ float  ats[64];
    __shared__ float4 hbf[4];

    if (t < HD) A2s[t] = *(const float4*)(A2 + t * 4);

    int idx = kg[p * KNN + k];
    int q = b * NPTS + idx;

    float r0 = xyzs[p*3+0] - xyzs[q*3+0];
    float r1 = xyzs[p*3+1] - xyzs[q*3+1];
    float r2 = xyzs[p*3+2] - xyzs[q*3+2];
    float h0 = fmaxf(r0*P1[0] + r1*P1[3] + r2*P1[6] + bp1[0], 0.f);
    float h1 = fmaxf(r0*P1[1] + r1*P1[4] + r2*P1[7] + bp1[1], 0.f);
    float h2 = fmaxf(r0*P1[2] + r1*P1[5] + r2*P1[8] + bp1[2], 0.f);
    if (g == 0) hs16[k] = make_float4(h0, h1, h2, 0.f);

    uint4 qu = *(const uint4*)(QKVb + p * WCOLS + c0);
    uint4 ku = *(const uint4*)(QKVb + q * WCOLS + HD + c0);
    uint4 vu = *(const uint4*)(QKVb + q * WCOLS + 2 * HD + c0);

    float qz[8] = { bf_lo(qu.x), bf_hi(qu.x), bf_lo(qu.y), bf_hi(qu.y),
                    bf_lo(qu.z), bf_hi(qu.z), bf_lo(qu.w), bf_hi(qu.w) };
    float kr[8] = { bf_lo(ku.x), bf_hi(ku.x), bf_lo(ku.y), bf_hi(ku.y),
                    bf_lo(ku.z), bf_hi(ku.z), bf_lo(ku.w), bf_hi(ku.w) };

    float wa0[8], wa1[8], wa2[8];
    *(float4*)(wa0)     = *(const float4*)(P2A1 + 0*HD + c0);
    *(float4*)(wa0 + 4) = *(const float4*)(P2A1 + 0*HD + c0 + 4);
    *(float4*)(wa1)     = *(const float4*)(P2A1 + 1*HD + c0);
    *(float4*)(wa1 + 4) = *(const float4*)(P2A1 + 1*HD + c0 + 4);
    *(float4*)(wa2)     = *(const float4*)(P2A1 + 2*HD + c0);
    *(float4*)(wa2 + 4) = *(const float4*)(P2A1 + 2*HD + c0 + 4);

    __syncthreads();   // A2s / hs16 visible

    float pl0 = 0.f, pl1 = 0.f, pl2 = 0.f, pl3 = 0.f;
    #pragma unroll
    for (int j = 0; j < 8; ++j) {
        float z = fmaxf(qz[j] - kr[j] + h0*wa0[j] + h1*wa1[j] + h2*wa2[j], 0.f);
        float4 ar = A2s[c0 + j];
        pl0 += z * ar.x; pl1 += z * ar.y; pl2 += z * ar.z; pl3 += z * ar.w;
    }
    pl0 += __shfl_xor(pl0, 16, 64); pl0 += __shfl_xor(pl0, 32, 64);
    pl1 += __shfl_xor(pl1, 16, 64); pl1 += __shfl_xor(pl1, 32, 64);
    pl2 += __shfl_xor(pl2, 16, 64); pl2 += __shfl_xor(pl2, 32, 64);
    pl3 += __shfl_xor(pl3, 16, 64); pl3 += __shfl_xor(pl3, 32, 64);
    if (lane < 16) lgp[w][lane] = make_float4(pl0, pl1, pl2, pl3);
    __syncthreads();

    if (t < 64) {
        int hh = t >> 4, kk = t & 15;
        const float* lp = (const float*)lgp;
        float lgt = b2[hh] + lp[0*64 + kk*4 + hh] + lp[1*64 + kk*4 + hh]
                           + lp[2*64 + kk*4 + hh] + lp[3*64 + kk*4 + hh];
        float m = ror_max16(lgt);
        float e = __expf(lgt - m);
        float s = ror_sum16(e);
        float a = e / s;
        ats[t] = a;
        float4 hv = hs16[kk];
        float hb0 = ror_sum16(a * hv.x);
        float hb1 = ror_sum16(a * hv.y);
        float hb2 = ror_sum16(a * hv.z);
        if (kk == 0) hbf[hh] = make_float4(hb0, hb1, hb2, 0.f);
    }
    __syncthreads();

    float a = ats[w * 16 + k];
    float vr[8] = { bf_lo(vu.x), bf_hi(vu.x), bf_lo(vu.y), bf_hi(vu.y),
                    bf_lo(vu.z), bf_hi(vu.z), bf_lo(vu.w), bf_hi(vu.w) };
    float wv[8];
    #pragma unroll
    for (int j = 0; j < 8; ++j) wv[j] = ror_sum16(a * vr[j]);

    if (k == 0) {
        float4 hb = hbf[w];
        float q0[8], q1[8], q2[8], bpv[8];
        *(float4*)(q0)     = *(const float4*)(P2 + 0*HD + c0);
        *(float4*)(q0 + 4) = *(const float4*)(P2 + 0*HD + c0 + 4);
        *(float4*)(q1)     = *(const float4*)(P2 + 1*HD + c0);
        *(float4*)(q1 + 4) = *(const float4*)(P2 + 1*HD + c0 + 4);
        *(float4*)(q2)     = *(const float4*)(P2 + 2*HD + c0);
        *(float4*)(q2 + 4) = *(const float4*)(P2 + 2*HD + c0 + 4);
        *(float4*)(bpv)     = *(const float4*)(bp2 + c0);
        *(float4*)(bpv + 4) = *(const float4*)(bp2 + c0 + 4);
        float f[8];
        #pragma unroll
        for (int j = 0; j < 8; ++j)
            f[j] = wv[j] + hb.x*q0[j] + hb.y*q1[j] + hb.z*q2[j] + bpv[j];
        uint4 fu;
        fu.x = pack2(f[0], f[1]); fu.y = pack2(f[2], f[3]);
        fu.z = pack2(f[4], f[5]); fu.w = pack2(f[6], f[7]);
        *(uint4*)(FUSEDb + p * HD + c0) = fu;
    }
}

// ---------------------------------------------------------------------------
// Kernel C (MFMA): out[16384][128] = FUSEDb @ Wout + bout (fp32 out).
// Block: 64 rows, 4 waves, K=128 (4 mfma/nt), nt=8.
// LDS stride 144 elems (288 B) -> conflict-free frag reads.
// ---------------------------------------------------------------------------
#define OK2 144
__global__ __launch_bounds__(256) void out_kernel(const unsigned short* __restrict__ FUSEDb,
                                                  const unsigned short* __restrict__ WoutT,
                                                  const float* __restrict__ bout,
                                                  float* __restrict__ out) {
    __shared__ unsigned short Af[64 * OK2];    // 18.4 KB
    __shared__ unsigned short Bf[HD * OK2];    // 36.9 KB
    int p0 = blockIdx.x * 64;
    int t = threadIdx.x;

    #pragma unroll
    for (int i = 0; i < 4; ++i) {              // stage A: 64 x 128 bf16
        int v = t + i * 256;
        int row = v >> 4, j16 = v & 15;
        *(uint4*)(&Af[row * OK2 + j16 * 8]) = ((const uint4*)FUSEDb)[(p0 + row) * 16 + j16];
    }
    #pragma unroll
    for (int i = 0; i < 8; ++i) {              // stage B: 128 x 128 bf16
        int v = t + i * 256;
        int n = v >> 4, j16 = v & 15;
        *(uint4*)(&Bf[n * OK2 + j16 * 8]) = ((const uint4*)WoutT)[v];
    }
    __syncthreads();

    int w = t >> 6, l = t & 63;
    int ml = l & 15, quad = l >> 4;
    int m0 = w * 16;

    short8 af[4];
    #pragma unroll
    for (int ks = 0; ks < 4; ++ks)
        af[ks] = *(const short8*)(&Af[(m0 + ml) * OK2 + ks * 32 + quad * 8]);

    #pragma unroll
    for (int nt = 0; nt < 8; ++nt) {
        float4v acc = {0.f, 0.f, 0.f, 0.f};
        #pragma unroll
        for (int ks = 0; ks < 4; ++ks) {
            short8 bf = *(const short8*)(&Bf[(nt * 16 + ml) * OK2 + ks * 32 + quad * 8]);
            acc = __builtin_amdgcn_mfma_f32_16x16x32_bf16(af[ks], bf, acc, 0, 0, 0);
        }
        int n = nt * 16 + ml;
        float bo = bout[n];
        #pragma unroll
        for (int r = 0; r < 4; ++r) {
            int row = p0 + m0 + quad * 4 + r;
            out[row * COUT + n] = acc[r] + bo;
        }
    }
}

// ---------------------------------------------------------------------------
extern "C" void kernel_launch(void* const* d_in, const int* in_sizes, int n_in,
                              void* d_out, int out_size, void* d_ws, size_t ws_size,
                              hipStream_t stream) {
    const float* xyzs = (const float*)d_in[0];
    const float* feat = (const float*)d_in[1];
    const int*   kg   = (const int*)  d_in[2];
    const float* Wk   = (const float*)d_in[3];
    const float* Wv   = (const float*)d_in[4];
    const float* Wq   = (const float*)d_in[5];
    const float* A1   = (const float*)d_in[6];
    const float* b1   = (const float*)d_in[7];
    const float* A2   = (const float*)d_in[8];
    const float* b2   = (const float*)d_in[9];
    const float* P1   = (const float*)d_in[10];
    const float* bp1  = (const float*)d_in[11];
    const float* P2   = (const float*)d_in[12];
    const float* bp2  = (const float*)d_in[13];
    const float* Wout = (const float*)d_in[14];
    const float* bout = (const float*)d_in[15];
    float* out = (float*)d_out;

    float* ws = (float*)d_ws;
    float* cvec = ws;                               // 128 fp32
    float* P2A1 = ws + 128;                         // 384 fp32  (total 512 fp32 = 2048 B)
    unsigned short* QKVb  = (unsigned short*)(ws + 512);         // BN*384 bf16 (12.6 MB)
    unsigned short* FUSEDb = QKVb + (size_t)BN * WCOLS;          // BN*128 bf16 (4 MB)
    unsigned short* WcatT = FUSEDb + (size_t)BN * HD;            // 384*64 bf16
    unsigned short* WoutT = WcatT + WCOLS * CIN;                 // 128*128 bf16

    int prep_elems = WCOLS*CIN + COUT*HD + 3*HD + HD;  // 41472
    prep_kernel<<<(prep_elems + 255) / 256, 256, 0, stream>>>(
        Wk, Wv, Wq, A1, b1, P2, bp2, Wout, WcatT, WoutT, P2A1, cvec);

    qkv_kernel<<<BN / 64, 256, 0, stream>>>(feat, WcatT, cvec, QKVb);

    attn_kernel<<<BN, 256, 0, stream>>>(
        xyzs, kg, QKVb, P1, bp1, P2, bp2, P2A1, A2, b2, FUSEDb);

    out_kernel<<<BN / 64, 256, 0, stream>>>(FUSEDb, WoutT, bout, out);
}